// Round 19
// baseline (464.931 us; speedup 1.0000x reference)
//
#include <hip/hip_runtime.h>
#include <hip/hip_bf16.h>

// GaussianPolicy: SNN-LIF frontend + 2-branch MLP heads.
// B=4096, IN=512, H=2048, A=32. fp32 in/out; fp16 MFMA compute internally.
// Trunk: m201-style 8-phase schedule (proven R18). LIF: 256x128, ring-3 LDS
// + DEFERRED slice processing (T15): acc->accS copy at slice start, LIF VALU
// split into 2 half-bursts overlapping later iters' MFMAs (no pipe drain).
// One mega-convert dispatch (R17).

typedef _Float16 f16;
using f32x4 = __attribute__((ext_vector_type(4))) float;
using f16x8 = __attribute__((ext_vector_type(8))) f16;   // 8 fp16 = 4 VGPRs

#define MFMA16(a, b, c) __builtin_amdgcn_mfma_f32_16x16x32_f16((a), (b), (c), 0, 0, 0)
#define VMW6()  asm volatile("s_waitcnt vmcnt(6)" ::: "memory")
#define VMW4()  asm volatile("s_waitcnt vmcnt(4)" ::: "memory")
#define VMW0()  asm volatile("s_waitcnt vmcnt(0)" ::: "memory")
#define LGKM0() asm volatile("s_waitcnt lgkmcnt(0)" ::: "memory")
#define BARRIER() __builtin_amdgcn_s_barrier()
#define SCHED0() __builtin_amdgcn_sched_barrier(0)

__device__ __forceinline__ void gload16(const void* g, void* l) {
  // async global->LDS, 16B/lane; LDS dest = wave-uniform base + lane*16
  __builtin_amdgcn_global_load_lds(
      (const __attribute__((address_space(1))) unsigned int*)g,
      (__attribute__((address_space(3))) unsigned int*)l, 16, 0, 0);
}

__device__ __forceinline__ void cvt8(const float4& a, const float4& b, f16* dst) {
  f16x8 d;
  d[0] = (f16)a.x; d[1] = (f16)a.y; d[2] = (f16)a.z; d[3] = (f16)a.w;
  d[4] = (f16)b.x; d[5] = (f16)b.y; d[6] = (f16)b.z; d[7] = (f16)b.w;
  *(f16x8*)dst = d;
}

// ---------------------------------------------------------------------------
// Mega-convert: all 8 fp32 tensors -> fp16, one dispatch (proven R17).
// ---------------------------------------------------------------------------
__global__ __launch_bounds__(256) void cvtall_kernel(
    const float* __restrict__ state, const float* __restrict__ wlif,
    const float* __restrict__ w11, const float* __restrict__ w21,
    const float* __restrict__ w12, const float* __restrict__ w22,
    const float* __restrict__ wm, const float* __restrict__ wls,
    f16* __restrict__ s16, f16* __restrict__ wl16, f16* __restrict__ w4,
    f16* __restrict__ wmh, f16* __restrict__ wlsh)
{
  int i = blockIdx.x * 256 + threadIdx.x;
  const float* src; f16* dst; int k, ks;
  if (i < 1310720)        { src = state; dst = s16;  k = i;           ks = k; }
  else if (i < 1441792)   { src = wlif;  dst = wl16; k = i - 1310720; ks = k; }
  else if (i < 3538944) {
    int j = i - 1441792; int w = j >> 19;
    src = (w == 0) ? w11 : (w == 1) ? w21 : (w == 2) ? w12 : w22;
    dst = w4; k = j; ks = j & 524287;
  }
  else if (i < 3547136)   { src = wm;  dst = wmh;  k = i - 3538944; ks = k; }
  else if (i < 3555328)   { src = wls; dst = wlsh; k = i - 3547136; ks = k; }
  else return;
  const float4* s4 = (const float4*)src;
  float4 a = s4[(size_t)ks * 2], b = s4[(size_t)ks * 2 + 1];
  cvt8(a, b, dst + (size_t)k * 8);
}

// ---------------------------------------------------------------------------
// LIF kernel. Tile 256x128, BK=64, 8 waves (4Mx2N), wave 64x64; 5 s-slices
// sequential; ring-3 LDS, stage-at-top, one barrier/iter. DEFERRED slice
// processing: at g%8==0 (g>0) copy acc->accS (post-barrier, no MFMA drain),
// zero acc; half-bursts at g%8==1 (mf 0-1) and g%8==3 (mf 2-3) read accS and
// overlap the current iter's independent MFMAs. Slice 4 finished post-loop.
// ---------------------------------------------------------------------------
__global__ __launch_bounds__(512, 1) void lif256_kernel(
    const f16* __restrict__ S,    // [4096*5, 512] fp16 (row (b*5+s))
    const f16* __restrict__ W,    // [2048, 512] fp16
    const float* __restrict__ bl, // [2048] fp32
    f16* __restrict__ X)          // [4096, 2048] fp16
{
  __shared__ alignas(16) f16 lds[73728];         // 144 KB: A@0, B@98304 bytes

  const int tid = threadIdx.x, wid = tid >> 6, lane = tid & 63;
  const int wg = ((int)blockIdx.x % 8) * 32 + (int)blockIdx.x / 8;
  const int bn = wg & 15, bm = wg >> 4;          // nbn=16, nbm=16
  const int b0 = bm * 256, h0 = bn * 128;
  const int wr0 = (wid >> 1) * 64, wc0 = (wid & 1) * 64;
  const int fr = lane & 15, fq = lane >> 4;
  const int sr = tid >> 3, scb = (tid & 7) * 16;  // staging row-in-64, col byte

  f32x4 acc[4][4] = {};
  f32x4 accS[4][4];                               // deferred slice copy
  float mem[4][4][4] = {};
  unsigned pcnt[4][4] = {};                       // byte r of pcnt = spike count

  // hoisted LDS read bases (BYTES, row stride 128 B)
  char* Lb = (char*)&lds[0];
  const int xsw = (fr & 7) << 4;
  const int x0 = (fq * 16) ^ xsw;
  const int x1 = (64 + fq * 16) ^ xsw;
  char* const pA0 = Lb + (wr0 + fr) * 128 + x0;
  char* const pA1 = Lb + (wr0 + fr) * 128 + x1;
  char* const pB0 = Lb + 98304 + (wc0 + fr) * 128 + x0;
  char* const pB1 = Lb + 98304 + (wc0 + fr) * 128 + x1;

  // hoisted staging bases (pre-swizzled source col)
  const f16* sBase[4]; const f16* wBase[2];
#pragma unroll
  for (int l = 0; l < 4; ++l) {
    const int row = l * 64 + sr;
    const int c2 = scb ^ ((row & 7) << 4);
    sBase[l] = S + (size_t)(b0 + row) * 2560 + (c2 >> 1);
  }
#pragma unroll
  for (int l = 0; l < 2; ++l) {
    const int row = l * 64 + sr;
    const int c2 = scb ^ ((row & 7) << 4);
    wBase[l] = W + (size_t)(h0 + row) * 512 + (c2 >> 1);
  }

  // stage tile g: A 4 gloads (8KB each), B 2 gloads
  auto STAGE = [&](int soA, int soB, int g) {
    const int koff = (g >> 3) * 512 + (g & 7) * 64;
    const int kw = (g & 7) * 64;
#pragma unroll
    for (int l = 0; l < 4; ++l)
      gload16(sBase[l] + koff, Lb + soA + l * 8192 + tid * 16);
#pragma unroll
    for (int l = 0; l < 2; ++l)
      gload16(wBase[l] + kw, Lb + 98304 + soB + l * 8192 + tid * 16);
  };

  const float bias[4] = { bl[h0 + wc0 + fr],      bl[h0 + wc0 + 16 + fr],
                          bl[h0 + wc0 + 32 + fr], bl[h0 + wc0 + 48 + fr] };

  STAGE(0, 0, 0);
  STAGE(32768, 16384, 1);
  VMW6();          // tile 0 landed (tile 1's 6 loads in flight)
  BARRIER();
  SCHED0();

  int soA = 0, soB = 0;                  // read offsets (slot g%3)
  int soStA = 65536, soStB = 32768;      // stage offsets (slot (g+2)%3)
  for (int g = 0; g < 40; ++g) {
    const int p = g & 7;

    // slice handoff: acc (completed last iter; a barrier since) -> accS
    if (p == 0 && g > 0) {
#pragma unroll
      for (int mf = 0; mf < 4; ++mf)
#pragma unroll
        for (int nf = 0; nf < 4; ++nf) {
          accS[mf][nf] = acc[mf][nf];
          acc[mf][nf] = f32x4{0.f, 0.f, 0.f, 0.f};
        }
    }

    if (g + 2 < 40) STAGE(soStA, soStB, g + 2);   // slot drained end of g-1
    SCHED0();

    // 16 ds_reads of slot g%3
    f16x8 b[4][2], a[4][2];
#pragma unroll
    for (int nf = 0; nf < 4; ++nf) {
      b[nf][0] = *(const f16x8*)(pB0 + soB + nf * 2048);
      b[nf][1] = *(const f16x8*)(pB1 + soB + nf * 2048);
    }
#pragma unroll
    for (int mf = 0; mf < 4; ++mf) {
      a[mf][0] = *(const f16x8*)(pA0 + soA + mf * 2048);
      a[mf][1] = *(const f16x8*)(pA1 + soA + mf * 2048);
    }

    __builtin_amdgcn_s_setprio(1);
#pragma unroll
    for (int mf = 0; mf < 4; ++mf)
#pragma unroll
      for (int nf = 0; nf < 4; ++nf) {
        acc[mf][nf] = MFMA16(a[mf][0], b[nf][0], acc[mf][nf]);
        acc[mf][nf] = MFMA16(a[mf][1], b[nf][1], acc[mf][nf]);
      }
    __builtin_amdgcn_s_setprio(0);

    // deferred LIF half-bursts (read accS; independent of in-flight MFMAs)
    if (p == 1 && g != 1) {
#pragma unroll
      for (int mf = 0; mf < 2; ++mf)
#pragma unroll
        for (int nf = 0; nf < 4; ++nf) {
          unsigned pc = pcnt[mf][nf];
#pragma unroll
          for (int r = 0; r < 4; ++r) {
            const float fc = accS[mf][nf][r] + bias[nf];
            float m = mem[mf][nf][r];
            const unsigned inc = 1u << (8 * r);
#pragma unroll
            for (int j = 0; j < 3; ++j) {
              m = ((m > 0.2f) ? 0.f : m * 0.2f) + fc;   // DECAY=0.2, spike resets
              pc += (m > 0.2f) ? inc : 0u;              // THRESH=0.2
            }
            mem[mf][nf][r] = m;
          }
          pcnt[mf][nf] = pc;
        }
    }
    if (p == 3 && g != 3) {
#pragma unroll
      for (int mf = 2; mf < 4; ++mf)
#pragma unroll
        for (int nf = 0; nf < 4; ++nf) {
          unsigned pc = pcnt[mf][nf];
#pragma unroll
          for (int r = 0; r < 4; ++r) {
            const float fc = accS[mf][nf][r] + bias[nf];
            float m = mem[mf][nf][r];
            const unsigned inc = 1u << (8 * r);
#pragma unroll
            for (int j = 0; j < 3; ++j) {
              m = ((m > 0.2f) ? 0.f : m * 0.2f) + fc;
              pc += (m > 0.2f) ? inc : 0u;
            }
            mem[mf][nf][r] = m;
          }
          pcnt[mf][nf] = pc;
        }
    }

    LGKM0();                              // my reads of this slot done
    if (g + 2 < 40)      { VMW6(); }      // tile g+1 landed (g+2's 6 flying)
    else if (g + 1 < 40) { VMW0(); }
    BARRIER();
    SCHED0();

    soA   = (soA   == 65536) ? 0 : soA   + 32768;
    soB   = (soB   == 32768) ? 0 : soB   + 16384;
    soStA = (soStA == 65536) ? 0 : soStA + 32768;
    soStB = (soStB == 32768) ? 0 : soStB + 16384;
  }

  // slice 4: process from acc directly
#pragma unroll
  for (int mf = 0; mf < 4; ++mf)
#pragma unroll
    for (int nf = 0; nf < 4; ++nf) {
      unsigned pc = pcnt[mf][nf];
#pragma unroll
      for (int r = 0; r < 4; ++r) {
        const float fc = acc[mf][nf][r] + bias[nf];
        float m = mem[mf][nf][r];
        const unsigned inc = 1u << (8 * r);
#pragma unroll
        for (int j = 0; j < 3; ++j) {
          m = ((m > 0.2f) ? 0.f : m * 0.2f) + fc;
          pc += (m > 0.2f) ? inc : 0u;
        }
        mem[mf][nf][r] = m;
      }
      pcnt[mf][nf] = pc;
    }

#pragma unroll
  for (int nf = 0; nf < 4; ++nf) {
    const int col = h0 + wc0 + nf * 16 + fr;
#pragma unroll
    for (int mf = 0; mf < 4; ++mf) {
      const int row0 = b0 + wr0 + mf * 16 + fq * 4;
#pragma unroll
      for (int r = 0; r < 4; ++r) {
        const float c = (float)((pcnt[mf][nf] >> (8 * r)) & 255u);
        X[(size_t)(row0 + r) * 2048 + col] = (f16)(c / 15.0f);
      }
    }
  }
}

// ---------------------------------------------------------------------------
// Trunk GEMM, m201-style 8-phase (proven R18): C = relu(A @ W^T + bias).
// 256x256 tile, 2 K-tiles (BK=64) per iter, 8 waves (2Mx4N), wave 128x64.
// LDS: Abuf0@0, Abuf1@32768, Bbuf0@65536, Bbuf1@98304 (tile t -> buf t&1).
// Phase p: {ds-reads; 1 half-tile stage; lgkm0; [vmcnt(4) at ph4/ph8];
// barrier; 16 MFMA}. Stage map (iter i): ph1/2 A(2i+1)->Abuf1, ph3/4
// B(2i+2)->Bbuf0, ph5/6 A(2i+2)->Abuf0, ph7/8 B(2i+3)->Bbuf1. NT=32.
// ---------------------------------------------------------------------------
__global__ __launch_bounds__(512, 2) void trunk256_kernel(
    const f16* __restrict__ A0, const f16* __restrict__ A1, int lda,
    const f16* __restrict__ W0, const f16* __restrict__ W1,
    const float* __restrict__ bb0, const float* __restrict__ bb1,
    f16* __restrict__ C0, f16* __restrict__ C1, int ldc,
    int nbm, int nbn_half, int K)
{
  __shared__ alignas(16) f16 lds[4][256 * 64];   // 128 KB

  const int tid = threadIdx.x, wid = tid >> 6, lane = tid & 63;
  const int nwg = nbm * nbn_half * 2, q8 = nwg / 8;
  const int wg = ((int)blockIdx.x % 8) * q8 + (int)blockIdx.x / 8;
  const int bmi = wg % nbm, t = wg / nbm;
  const int half = (t >= nbn_half);
  const f16* Ap = half ? A1 : A0;
  const f16* Wp = half ? W1 : W0;
  const float* bias = half ? bb1 : bb0;
  f16* C = half ? C1 : C0;
  const int bm0 = bmi * 256;
  const int bn0 = (half ? t - nbn_half : t) * 256;

  const int wr0 = (wid >> 2) * 128, wc0 = (wid & 3) * 64;
  const int fr = lane & 15, fq = lane >> 4;
  const int sr = tid >> 3, scb = (tid & 7) * 16;

  f32x4 acc[8][4] = {};

  // hoisted LDS read bases (BYTES, row stride 128 B)
  char* Lb = (char*)&lds[0][0];
  const int xsw = (fr & 7) << 4;
  const int x0 = (fq * 16) ^ xsw;
  const int x1 = (64 + fq * 16) ^ xsw;
  char* const pA0 = Lb + (wr0 + fr) * 128 + x0;
  char* const pA1 = Lb + (wr0 + fr) * 128 + x1;
  char* const pB0 = Lb + 65536 + (wc0 + fr) * 128 + x0;
  char* const pB1 = Lb + 65536 + (wc0 + fr) * 128 + x1;

  // hoisted staging bases
  const f16* aBase[4]; const f16* wBase[4];
#pragma unroll
  for (int l = 0; l < 4; ++l) {
    const int row = l * 64 + sr;
    const int c2 = scb ^ ((row & 7) << 4);
    aBase[l] = Ap + (size_t)(bm0 + row) * lda + (c2 >> 1);
    wBase[l] = Wp + (size_t)(bn0 + row) * K + (c2 >> 1);
  }

  auto STG_A = [&](int bufoff, int h, int kt) {
    const int koff = kt * 64;
#pragma unroll
    for (int l = 2 * h; l < 2 * h + 2; ++l)
      gload16(aBase[l] + koff, Lb + bufoff + l * 8192 + tid * 16);
  };
  auto STG_B = [&](int bufoff, int h, int kt) {
    const int koff = kt * 64;
#pragma unroll
    for (int l = 2 * h; l < 2 * h + 2; ++l)
      gload16(wBase[l] + koff, Lb + 65536 + bufoff + l * 8192 + tid * 16);
  };

  auto QUAD = [&](int mbase, f16x8 (&b)[4][2], f16x8 (&a)[2][2]) {
    __builtin_amdgcn_s_setprio(1);
#pragma unroll
    for (int nf = 0; nf < 4; ++nf) {
      acc[mbase][nf]     = MFMA16(a[0][0], b[nf][0], acc[mbase][nf]);
      acc[mbase][nf]     = MFMA16(a[0][1], b[nf][1], acc[mbase][nf]);
      acc[mbase + 1][nf] = MFMA16(a[1][0], b[nf][0], acc[mbase + 1][nf]);
      acc[mbase + 1][nf] = MFMA16(a[1][1], b[nf][1], acc[mbase + 1][nf]);
    }
    __builtin_amdgcn_s_setprio(0);
  };

  // prologue: B(0), A(0) -> buf0; B(1) -> Bbuf1. A(1) staged in iter0 ph1/2.
  STG_B(0, 0, 0); STG_B(0, 1, 0);
  STG_A(0, 0, 0); STG_A(0, 1, 0);
  STG_B(32768, 0, 1); STG_B(32768, 1, 1);
  VMW0();
  BARRIER();
  SCHED0();

  f16x8 b[4][2], a[2][2];
  for (int i = 0; i < 16; ++i) {
    const int t1 = 2 * i + 1, u = 2 * i + 2, v = 2 * i + 3;
    const bool su = (u < 32), sv = (v < 32);

    // ---- ph1: B(t0)@Bbuf0 + A-q0(t0)@Abuf0; stage A-h0(t1)->Abuf1
#pragma unroll
    for (int nf = 0; nf < 4; ++nf) {
      b[nf][0] = *(const f16x8*)(pB0 + nf * 2048);
      b[nf][1] = *(const f16x8*)(pB1 + nf * 2048);
    }
#pragma unroll
    for (int j = 0; j < 2; ++j) {
      a[j][0] = *(const f16x8*)(pA0 + j * 2048);
      a[j][1] = *(const f16x8*)(pA1 + j * 2048);
    }
    STG_A(32768, 0, t1);
    LGKM0(); BARRIER(); SCHED0();
    QUAD(0, b, a);

    // ---- ph2: A-q1(t0); stage A-h1(t1)
#pragma unroll
    for (int j = 0; j < 2; ++j) {
      a[j][0] = *(const f16x8*)(pA0 + (2 + j) * 2048);
      a[j][1] = *(const f16x8*)(pA1 + (2 + j) * 2048);
    }
    STG_A(32768, 1, t1);
    LGKM0(); BARRIER(); SCHED0();
    QUAD(2, b, a);

    // ---- ph3: A-q2(t0); stage B-h0(u)->Bbuf0 (freed at ph1 barrier)
#pragma unroll
    for (int j = 0; j < 2; ++j) {
      a[j][0] = *(const f16x8*)(pA0 + (4 + j) * 2048);
      a[j][1] = *(const f16x8*)(pA1 + (4 + j) * 2048);
    }
    if (su) STG_B(0, 0, u);
    LGKM0(); BARRIER(); SCHED0();
    QUAD(4, b, a);

    // ---- ph4: A-q3(t0); stage B-h1(u); vmcnt(4) => A(t1) landed
#pragma unroll
    for (int j = 0; j < 2; ++j) {
      a[j][0] = *(const f16x8*)(pA0 + (6 + j) * 2048);
      a[j][1] = *(const f16x8*)(pA1 + (6 + j) * 2048);
    }
    if (su) STG_B(0, 1, u);
    LGKM0();
    if (su) { VMW4(); } else { VMW0(); }
    BARRIER(); SCHED0();
    QUAD(6, b, a);

    // ---- ph5: B(t1)@Bbuf1 + A-q0(t1)@Abuf1; stage A-h0(u)->Abuf0
#pragma unroll
    for (int nf = 0; nf < 4; ++nf) {
      b[nf][0] = *(const f16x8*)(pB0 + 32768 + nf * 2048);
      b[nf][1] = *(const f16x8*)(pB1 + 32768 + nf * 2048);
    }
#pragma unroll
    for (int j = 0; j < 2; ++j) {
      a[j][0] = *(const f16x8*)(pA0 + 32768 + j * 2048);
      a[j][1] = *(const f16x8*)(pA1 + 32768 + j * 2048);
    }
    if (su) STG_A(0, 0, u);
    LGKM0(); BARRIER(); SCHED0();
    QUAD(0, b, a);

    // ---- ph6: A-q1(t1); stage A-h1(u)
#pragma unroll
    for (int j = 0; j < 2; ++j) {
      a[j][0] = *(const f16x8*)(pA0 + 32768 + (2 + j) * 2048);
      a[j][1] = *(const f16x8*)(pA1 + 32768 + (2 + j) * 2048);
    }
    if (su) STG_A(0, 1, u);
    LGKM0(); BARRIER(); SCHED0();
    QUAD(2, b, a);

    // ---- ph7: A-q2(t1); stage B-h0(v)->Bbuf1 (freed at ph5 barrier)
#pragma unroll
    for (int j = 0; j < 2; ++j) {
      a[j][0] = *(const f16x8*)(pA0 + 32768 + (4 + j) * 2048);
      a[j][1] = *(const f16x8*)(pA1 + 32768 + (4 + j) * 2048);
    }
    if (sv) STG_B(32768, 0, v);
    LGKM0(); BARRIER(); SCHED0();
    QUAD(4, b, a);

    // ---- ph8: A-q3(t1); stage B-h1(v); vmcnt(4) => thru A(u) landed
#pragma unroll
    for (int j = 0; j < 2; ++j) {
      a[j][0] = *(const f16x8*)(pA0 + 32768 + (6 + j) * 2048);
      a[j][1] = *(const f16x8*)(pA1 + 32768 + (6 + j) * 2048);
    }
    if (sv) STG_B(32768, 1, v);
    LGKM0();
    if (sv) { VMW4(); } else { VMW0(); }
    BARRIER(); SCHED0();
    QUAD(6, b, a);
  }

#pragma unroll
  for (int nf = 0; nf < 4; ++nf) {
    const int col = bn0 + wc0 + nf * 16 + fr;
    const float bv = bias[col];
#pragma unroll
    for (int m = 0; m < 8; ++m) {
      const int row0 = bm0 + wr0 + m * 16 + fq * 4;
#pragma unroll
      for (int r = 0; r < 4; ++r) {
        float v = fmaxf(acc[m][nf][r] + bv, 0.f);
        C[(size_t)(row0 + r) * ldc + col] = (f16)v;
      }
    }
  }
}

// ---------------------------------------------------------------------------
// Heads: mean = h12@Wm^T + bm ; log_std = clip(h22@Wls^T + bls, -20, 2). fp32 out.
// ---------------------------------------------------------------------------
__global__ __launch_bounds__(256) void head_kernel(
    const f16* __restrict__ H1, const f16* __restrict__ H2,
    const f16* __restrict__ Wm, const float* __restrict__ bm,
    const f16* __restrict__ Wls, const float* __restrict__ bls,
    float* __restrict__ OUT, int M, int K)
{
  const int tid = threadIdx.x, wid = tid >> 6, lane = tid & 63;
  const int m0 = blockIdx.x * 64 + wid * 16;
  const int kb = (lane >> 4) * 8, fr = lane & 15, fq = lane >> 4;

  f32x4 a1[2] = {}, a2[2] = {};
  for (int k0 = 0; k0 < K; k0 += 32) {
    f16x8 f1 = *(const f16x8*)&H1[(size_t)(m0 + fr) * K + k0 + kb];
    f16x8 f2 = *(const f16x8*)&H2[(size_t)(m0 + fr) * K + k0 + kb];
#pragma unroll
    for (int n = 0; n < 2; ++n) {
      f16x8 wm = *(const f16x8*)&Wm[(size_t)(n * 16 + fr) * K + k0 + kb];
      f16x8 wl = *(const f16x8*)&Wls[(size_t)(n * 16 + fr) * K + k0 + kb];
      a1[n] = MFMA16(f1, wm, a1[n]);
      a2[n] = MFMA16(f2, wl, a2[n]);
    }
  }

#pragma unroll
  for (int n = 0; n < 2; ++n) {
    const int col = n * 16 + fr;
    const float bvm = bm[col];
    const float bvl = bls[col];
#pragma unroll
    for (int r = 0; r < 4; ++r) {
      const int row = m0 + fq * 4 + r;
      OUT[(size_t)row * 32 + col] = a1[n][r] + bvm;
      float lv = a2[n][r] + bvl;
      OUT[(size_t)M * 32 + (size_t)row * 32 + col] = fminf(fmaxf(lv, -20.f), 2.f);
    }
  }
}

// ---------------------------------------------------------------------------
extern "C" void kernel_launch(void* const* d_in, const int* in_sizes, int n_in,
                              void* d_out, int out_size, void* d_ws, size_t ws_size,
                              hipStream_t stream) {
  const float* state = (const float*)d_in[0];
  const float* W_lif = (const float*)d_in[1];
  const float* b_lif = (const float*)d_in[2];
  const float* W11   = (const float*)d_in[3];
  const float* b11   = (const float*)d_in[4];
  const float* W12   = (const float*)d_in[5];
  const float* b12   = (const float*)d_in[6];
  const float* W21   = (const float*)d_in[7];
  const float* b21   = (const float*)d_in[8];
  const float* W22   = (const float*)d_in[9];
  const float* b22   = (const float*)d_in[10];
  const float* Wm    = (const float*)d_in[11];
  const float* bm    = (const float*)d_in[12];
  const float* Wls   = (const float*)d_in[13];
  const float* bls   = (const float*)d_in[14];
  float* out = (float*)d_out;

  const int B = 4096, H = 2048;
  char* ws = (char*)d_ws;
  // layout (bytes), peak 84,148,224:
  f16* x    = (f16*)(ws);
  f16* s16  = (f16*)(ws + 16777216);
  f16* h1   = (f16*)(ws + 16777216);
  f16* h2   = (f16*)(ws + 33554432);
  f16* wl16 = (f16*)(ws + 37748736);
  f16* w4   = (f16*)(ws + 50331648);
  f16* w11h = (f16*)(ws + 50331648);
  f16* w21h = (f16*)(ws + 58720256);
  f16* h22  = (f16*)(ws + 50331648);
  f16* w12h = (f16*)(ws + 67108864);
  f16* w22h = (f16*)(ws + 75497472);
  f16* wmh  = (f16*)(ws + 83886080);
  f16* wlsh = (f16*)(ws + 84017152);
  f16* h12  = x;

  // 1) ALL converts in one dispatch
  cvtall_kernel<<<13888, 256, 0, stream>>>(
      state, W_lif, W11, W21, W12, W22, Wm, Wls,
      s16, wl16, w4, wmh, wlsh);

  // 2) fused fc-GEMM + LIF -> x
  lif256_kernel<<<256, 512, 0, stream>>>(s16, wl16, b_lif, x);

  // 3) trunk layer-1 (fused dual-output; h1/h2 overwrite dead s16/wl16)
  trunk256_kernel<<<256, 512, 0, stream>>>(x, x, H, w11h, w21h, b11, b21,
                                           h1, h2, H, 16, 8, H);
  // 4) trunk layer-2 -> h12 (over x), h22 (over dead w11h/w21h)
  trunk256_kernel<<<256, 512, 0, stream>>>(h1, h2, H, w12h, w22h, b12, b22,
                                           h12, h22, H, 16, 8, H);

  // 5) heads -> d_out = [mean | log_std] fp32
  head_kernel<<<B / 64, 256, 0, stream>>>(h12, h22, wmh, bm, wlsh, bls, out, B, H);
}

// Round 20
// 255.103 us; speedup vs baseline: 1.8225x; 1.8225x over previous
//
#include <hip/hip_runtime.h>
#include <hip/hip_bf16.h>

// GaussianPolicy: SNN-LIF frontend + 2-branch MLP heads.
// B=4096, IN=512, H=2048, A=32. fp32 in/out; fp16 MFMA compute internally.
// Trunk: m201-style 8-phase schedule (proven R18). LIF: 256x128, ring-3 LDS;
// LIF burst at TOP of the iter after each slice completes (no MFMA-pipe
// drain, no extra registers). One mega-convert dispatch (R17).

typedef _Float16 f16;
using f32x4 = __attribute__((ext_vector_type(4))) float;
using f16x8 = __attribute__((ext_vector_type(8))) f16;   // 8 fp16 = 4 VGPRs

#define MFMA16(a, b, c) __builtin_amdgcn_mfma_f32_16x16x32_f16((a), (b), (c), 0, 0, 0)
#define VMW6()  asm volatile("s_waitcnt vmcnt(6)" ::: "memory")
#define VMW4()  asm volatile("s_waitcnt vmcnt(4)" ::: "memory")
#define VMW0()  asm volatile("s_waitcnt vmcnt(0)" ::: "memory")
#define LGKM0() asm volatile("s_waitcnt lgkmcnt(0)" ::: "memory")
#define BARRIER() __builtin_amdgcn_s_barrier()
#define SCHED0() __builtin_amdgcn_sched_barrier(0)

__device__ __forceinline__ void gload16(const void* g, void* l) {
  // async global->LDS, 16B/lane; LDS dest = wave-uniform base + lane*16
  __builtin_amdgcn_global_load_lds(
      (const __attribute__((address_space(1))) unsigned int*)g,
      (__attribute__((address_space(3))) unsigned int*)l, 16, 0, 0);
}

__device__ __forceinline__ void cvt8(const float4& a, const float4& b, f16* dst) {
  f16x8 d;
  d[0] = (f16)a.x; d[1] = (f16)a.y; d[2] = (f16)a.z; d[3] = (f16)a.w;
  d[4] = (f16)b.x; d[5] = (f16)b.y; d[6] = (f16)b.z; d[7] = (f16)b.w;
  *(f16x8*)dst = d;
}

// ---------------------------------------------------------------------------
// Mega-convert: all 8 fp32 tensors -> fp16, one dispatch (proven R17).
// ---------------------------------------------------------------------------
__global__ __launch_bounds__(256) void cvtall_kernel(
    const float* __restrict__ state, const float* __restrict__ wlif,
    const float* __restrict__ w11, const float* __restrict__ w21,
    const float* __restrict__ w12, const float* __restrict__ w22,
    const float* __restrict__ wm, const float* __restrict__ wls,
    f16* __restrict__ s16, f16* __restrict__ wl16, f16* __restrict__ w4,
    f16* __restrict__ wmh, f16* __restrict__ wlsh)
{
  int i = blockIdx.x * 256 + threadIdx.x;
  const float* src; f16* dst; int k, ks;
  if (i < 1310720)        { src = state; dst = s16;  k = i;           ks = k; }
  else if (i < 1441792)   { src = wlif;  dst = wl16; k = i - 1310720; ks = k; }
  else if (i < 3538944) {
    int j = i - 1441792; int w = j >> 19;
    src = (w == 0) ? w11 : (w == 1) ? w21 : (w == 2) ? w12 : w22;
    dst = w4; k = j; ks = j & 524287;
  }
  else if (i < 3547136)   { src = wm;  dst = wmh;  k = i - 3538944; ks = k; }
  else if (i < 3555328)   { src = wls; dst = wlsh; k = i - 3547136; ks = k; }
  else return;
  const float4* s4 = (const float4*)src;
  float4 a = s4[(size_t)ks * 2], b = s4[(size_t)ks * 2 + 1];
  cvt8(a, b, dst + (size_t)k * 8);
}

// ---------------------------------------------------------------------------
// LIF kernel. Tile 256x128, BK=64, 8 waves (4Mx2N), wave 64x64; 5 s-slices
// sequential; ring-3 LDS, stage-at-top, one barrier/iter. LIF burst for
// slice s runs at the TOP of iter g=8(s+1) (acc completed last iter; the
// intervening waits/barrier hide the MFMA latency); burst reads acc in
// place then zeroes it. Slice 4 finalized post-loop. No extra registers.
// ---------------------------------------------------------------------------
__global__ __launch_bounds__(512, 1) void lif256_kernel(
    const f16* __restrict__ S,    // [4096*5, 512] fp16 (row (b*5+s))
    const f16* __restrict__ W,    // [2048, 512] fp16
    const float* __restrict__ bl, // [2048] fp32
    f16* __restrict__ X)          // [4096, 2048] fp16
{
  __shared__ alignas(16) f16 lds[73728];         // 144 KB: A@0, B@98304 bytes

  const int tid = threadIdx.x, wid = tid >> 6, lane = tid & 63;
  const int wg = ((int)blockIdx.x % 8) * 32 + (int)blockIdx.x / 8;
  const int bn = wg & 15, bm = wg >> 4;          // nbn=16, nbm=16
  const int b0 = bm * 256, h0 = bn * 128;
  const int wr0 = (wid >> 1) * 64, wc0 = (wid & 1) * 64;
  const int fr = lane & 15, fq = lane >> 4;
  const int sr = tid >> 3, scb = (tid & 7) * 16;  // staging row-in-64, col byte

  f32x4 acc[4][4] = {};
  float mem[4][4][4] = {};
  unsigned pcnt[4][4] = {};                       // byte r of pcnt = spike count

  // hoisted LDS read bases (BYTES, row stride 128 B)
  char* Lb = (char*)&lds[0];
  const int xsw = (fr & 7) << 4;
  const int x0 = (fq * 16) ^ xsw;
  const int x1 = (64 + fq * 16) ^ xsw;
  char* const pA0 = Lb + (wr0 + fr) * 128 + x0;
  char* const pA1 = Lb + (wr0 + fr) * 128 + x1;
  char* const pB0 = Lb + 98304 + (wc0 + fr) * 128 + x0;
  char* const pB1 = Lb + 98304 + (wc0 + fr) * 128 + x1;

  // hoisted staging bases (pre-swizzled source col)
  const f16* sBase[4]; const f16* wBase[2];
#pragma unroll
  for (int l = 0; l < 4; ++l) {
    const int row = l * 64 + sr;
    const int c2 = scb ^ ((row & 7) << 4);
    sBase[l] = S + (size_t)(b0 + row) * 2560 + (c2 >> 1);
  }
#pragma unroll
  for (int l = 0; l < 2; ++l) {
    const int row = l * 64 + sr;
    const int c2 = scb ^ ((row & 7) << 4);
    wBase[l] = W + (size_t)(h0 + row) * 512 + (c2 >> 1);
  }

  // stage tile g: A 4 gloads (8KB each), B 2 gloads
  auto STAGE = [&](int soA, int soB, int g) {
    const int koff = (g >> 3) * 512 + (g & 7) * 64;
    const int kw = (g & 7) * 64;
#pragma unroll
    for (int l = 0; l < 4; ++l)
      gload16(sBase[l] + koff, Lb + soA + l * 8192 + tid * 16);
#pragma unroll
    for (int l = 0; l < 2; ++l)
      gload16(wBase[l] + kw, Lb + 98304 + soB + l * 8192 + tid * 16);
  };

  const float bias[4] = { bl[h0 + wc0 + fr],      bl[h0 + wc0 + 16 + fr],
                          bl[h0 + wc0 + 32 + fr], bl[h0 + wc0 + 48 + fr] };

  // LIF burst over the completed slice in acc; then reset acc.
  auto LIFBURST = [&]() {
#pragma unroll
    for (int mf = 0; mf < 4; ++mf)
#pragma unroll
      for (int nf = 0; nf < 4; ++nf) {
        unsigned pc = pcnt[mf][nf];
#pragma unroll
        for (int r = 0; r < 4; ++r) {
          const float fc = acc[mf][nf][r] + bias[nf];
          float m = mem[mf][nf][r];
          const unsigned inc = 1u << (8 * r);
#pragma unroll
          for (int j = 0; j < 3; ++j) {
            m = ((m > 0.2f) ? 0.f : m * 0.2f) + fc;   // DECAY=0.2, spike resets
            pc += (m > 0.2f) ? inc : 0u;              // THRESH=0.2
          }
          mem[mf][nf][r] = m;
        }
        pcnt[mf][nf] = pc;
        acc[mf][nf] = f32x4{0.f, 0.f, 0.f, 0.f};
      }
  };

  STAGE(0, 0, 0);
  STAGE(32768, 16384, 1);
  VMW6();          // tile 0 landed (tile 1's 6 loads in flight)
  BARRIER();
  SCHED0();

  int soA = 0, soB = 0;                  // read offsets (slot g%3)
  int soStA = 65536, soStB = 32768;      // stage offsets (slot (g+2)%3)
  for (int g = 0; g < 40; ++g) {
    if (g + 2 < 40) STAGE(soStA, soStB, g + 2);   // slot drained end of g-1
    SCHED0();

    // slice handoff at top of iter (acc finished last iter; the barrier +
    // stage-issue interval hid the MFMA latency — no pipe drain here)
    if ((g & 7) == 0 && g > 0) LIFBURST();

    // 16 ds_reads of slot g%3
    f16x8 b[4][2], a[4][2];
#pragma unroll
    for (int nf = 0; nf < 4; ++nf) {
      b[nf][0] = *(const f16x8*)(pB0 + soB + nf * 2048);
      b[nf][1] = *(const f16x8*)(pB1 + soB + nf * 2048);
    }
#pragma unroll
    for (int mf = 0; mf < 4; ++mf) {
      a[mf][0] = *(const f16x8*)(pA0 + soA + mf * 2048);
      a[mf][1] = *(const f16x8*)(pA1 + soA + mf * 2048);
    }

    __builtin_amdgcn_s_setprio(1);
#pragma unroll
    for (int mf = 0; mf < 4; ++mf)
#pragma unroll
      for (int nf = 0; nf < 4; ++nf) {
        acc[mf][nf] = MFMA16(a[mf][0], b[nf][0], acc[mf][nf]);
        acc[mf][nf] = MFMA16(a[mf][1], b[nf][1], acc[mf][nf]);
      }
    __builtin_amdgcn_s_setprio(0);

    LGKM0();                              // my reads of this slot done
    if (g + 2 < 40)      { VMW6(); }      // tile g+1 landed (g+2's 6 flying)
    else if (g + 1 < 40) { VMW0(); }
    BARRIER();
    SCHED0();

    soA   = (soA   == 65536) ? 0 : soA   + 32768;
    soB   = (soB   == 32768) ? 0 : soB   + 16384;
    soStA = (soStA == 65536) ? 0 : soStA + 32768;
    soStB = (soStB == 32768) ? 0 : soStB + 16384;
  }

  // slice 4: finalize from acc
  LIFBURST();

#pragma unroll
  for (int nf = 0; nf < 4; ++nf) {
    const int col = h0 + wc0 + nf * 16 + fr;
#pragma unroll
    for (int mf = 0; mf < 4; ++mf) {
      const int row0 = b0 + wr0 + mf * 16 + fq * 4;
#pragma unroll
      for (int r = 0; r < 4; ++r) {
        const float c = (float)((pcnt[mf][nf] >> (8 * r)) & 255u);
        X[(size_t)(row0 + r) * 2048 + col] = (f16)(c / 15.0f);
      }
    }
  }
}

// ---------------------------------------------------------------------------
// Trunk GEMM, m201-style 8-phase (proven R18): C = relu(A @ W^T + bias).
// 256x256 tile, 2 K-tiles (BK=64) per iter, 8 waves (2Mx4N), wave 128x64.
// LDS: Abuf0@0, Abuf1@32768, Bbuf0@65536, Bbuf1@98304 (tile t -> buf t&1).
// Phase p: {ds-reads; 1 half-tile stage; lgkm0; [vmcnt(4) at ph4/ph8];
// barrier; 16 MFMA}. Stage map (iter i): ph1/2 A(2i+1)->Abuf1, ph3/4
// B(2i+2)->Bbuf0, ph5/6 A(2i+2)->Abuf0, ph7/8 B(2i+3)->Bbuf1. NT=32.
// ---------------------------------------------------------------------------
__global__ __launch_bounds__(512, 2) void trunk256_kernel(
    const f16* __restrict__ A0, const f16* __restrict__ A1, int lda,
    const f16* __restrict__ W0, const f16* __restrict__ W1,
    const float* __restrict__ bb0, const float* __restrict__ bb1,
    f16* __restrict__ C0, f16* __restrict__ C1, int ldc,
    int nbm, int nbn_half, int K)
{
  __shared__ alignas(16) f16 lds[4][256 * 64];   // 128 KB

  const int tid = threadIdx.x, wid = tid >> 6, lane = tid & 63;
  const int nwg = nbm * nbn_half * 2, q8 = nwg / 8;
  const int wg = ((int)blockIdx.x % 8) * q8 + (int)blockIdx.x / 8;
  const int bmi = wg % nbm, t = wg / nbm;
  const int half = (t >= nbn_half);
  const f16* Ap = half ? A1 : A0;
  const f16* Wp = half ? W1 : W0;
  const float* bias = half ? bb1 : bb0;
  f16* C = half ? C1 : C0;
  const int bm0 = bmi * 256;
  const int bn0 = (half ? t - nbn_half : t) * 256;

  const int wr0 = (wid >> 2) * 128, wc0 = (wid & 3) * 64;
  const int fr = lane & 15, fq = lane >> 4;
  const int sr = tid >> 3, scb = (tid & 7) * 16;

  f32x4 acc[8][4] = {};

  // hoisted LDS read bases (BYTES, row stride 128 B)
  char* Lb = (char*)&lds[0][0];
  const int xsw = (fr & 7) << 4;
  const int x0 = (fq * 16) ^ xsw;
  const int x1 = (64 + fq * 16) ^ xsw;
  char* const pA0 = Lb + (wr0 + fr) * 128 + x0;
  char* const pA1 = Lb + (wr0 + fr) * 128 + x1;
  char* const pB0 = Lb + 65536 + (wc0 + fr) * 128 + x0;
  char* const pB1 = Lb + 65536 + (wc0 + fr) * 128 + x1;

  // hoisted staging bases
  const f16* aBase[4]; const f16* wBase[4];
#pragma unroll
  for (int l = 0; l < 4; ++l) {
    const int row = l * 64 + sr;
    const int c2 = scb ^ ((row & 7) << 4);
    aBase[l] = Ap + (size_t)(bm0 + row) * lda + (c2 >> 1);
    wBase[l] = Wp + (size_t)(bn0 + row) * K + (c2 >> 1);
  }

  auto STG_A = [&](int bufoff, int h, int kt) {
    const int koff = kt * 64;
#pragma unroll
    for (int l = 2 * h; l < 2 * h + 2; ++l)
      gload16(aBase[l] + koff, Lb + bufoff + l * 8192 + tid * 16);
  };
  auto STG_B = [&](int bufoff, int h, int kt) {
    const int koff = kt * 64;
#pragma unroll
    for (int l = 2 * h; l < 2 * h + 2; ++l)
      gload16(wBase[l] + koff, Lb + 65536 + bufoff + l * 8192 + tid * 16);
  };

  auto QUAD = [&](int mbase, f16x8 (&b)[4][2], f16x8 (&a)[2][2]) {
    __builtin_amdgcn_s_setprio(1);
#pragma unroll
    for (int nf = 0; nf < 4; ++nf) {
      acc[mbase][nf]     = MFMA16(a[0][0], b[nf][0], acc[mbase][nf]);
      acc[mbase][nf]     = MFMA16(a[0][1], b[nf][1], acc[mbase][nf]);
      acc[mbase + 1][nf] = MFMA16(a[1][0], b[nf][0], acc[mbase + 1][nf]);
      acc[mbase + 1][nf] = MFMA16(a[1][1], b[nf][1], acc[mbase + 1][nf]);
    }
    __builtin_amdgcn_s_setprio(0);
  };

  // prologue: B(0), A(0) -> buf0; B(1) -> Bbuf1. A(1) staged in iter0 ph1/2.
  STG_B(0, 0, 0); STG_B(0, 1, 0);
  STG_A(0, 0, 0); STG_A(0, 1, 0);
  STG_B(32768, 0, 1); STG_B(32768, 1, 1);
  VMW0();
  BARRIER();
  SCHED0();

  f16x8 b[4][2], a[2][2];
  for (int i = 0; i < 16; ++i) {
    const int t1 = 2 * i + 1, u = 2 * i + 2, v = 2 * i + 3;
    const bool su = (u < 32), sv = (v < 32);

    // ---- ph1: B(t0)@Bbuf0 + A-q0(t0)@Abuf0; stage A-h0(t1)->Abuf1
#pragma unroll
    for (int nf = 0; nf < 4; ++nf) {
      b[nf][0] = *(const f16x8*)(pB0 + nf * 2048);
      b[nf][1] = *(const f16x8*)(pB1 + nf * 2048);
    }
#pragma unroll
    for (int j = 0; j < 2; ++j) {
      a[j][0] = *(const f16x8*)(pA0 + j * 2048);
      a[j][1] = *(const f16x8*)(pA1 + j * 2048);
    }
    STG_A(32768, 0, t1);
    LGKM0(); BARRIER(); SCHED0();
    QUAD(0, b, a);

    // ---- ph2: A-q1(t0); stage A-h1(t1)
#pragma unroll
    for (int j = 0; j < 2; ++j) {
      a[j][0] = *(const f16x8*)(pA0 + (2 + j) * 2048);
      a[j][1] = *(const f16x8*)(pA1 + (2 + j) * 2048);
    }
    STG_A(32768, 1, t1);
    LGKM0(); BARRIER(); SCHED0();
    QUAD(2, b, a);

    // ---- ph3: A-q2(t0); stage B-h0(u)->Bbuf0 (freed at ph1 barrier)
#pragma unroll
    for (int j = 0; j < 2; ++j) {
      a[j][0] = *(const f16x8*)(pA0 + (4 + j) * 2048);
      a[j][1] = *(const f16x8*)(pA1 + (4 + j) * 2048);
    }
    if (su) STG_B(0, 0, u);
    LGKM0(); BARRIER(); SCHED0();
    QUAD(4, b, a);

    // ---- ph4: A-q3(t0); stage B-h1(u); vmcnt(4) => A(t1) landed
#pragma unroll
    for (int j = 0; j < 2; ++j) {
      a[j][0] = *(const f16x8*)(pA0 + (6 + j) * 2048);
      a[j][1] = *(const f16x8*)(pA1 + (6 + j) * 2048);
    }
    if (su) STG_B(0, 1, u);
    LGKM0();
    if (su) { VMW4(); } else { VMW0(); }
    BARRIER(); SCHED0();
    QUAD(6, b, a);

    // ---- ph5: B(t1)@Bbuf1 + A-q0(t1)@Abuf1; stage A-h0(u)->Abuf0
#pragma unroll
    for (int nf = 0; nf < 4; ++nf) {
      b[nf][0] = *(const f16x8*)(pB0 + 32768 + nf * 2048);
      b[nf][1] = *(const f16x8*)(pB1 + 32768 + nf * 2048);
    }
#pragma unroll
    for (int j = 0; j < 2; ++j) {
      a[j][0] = *(const f16x8*)(pA0 + 32768 + j * 2048);
      a[j][1] = *(const f16x8*)(pA1 + 32768 + j * 2048);
    }
    if (su) STG_A(0, 0, u);
    LGKM0(); BARRIER(); SCHED0();
    QUAD(0, b, a);

    // ---- ph6: A-q1(t1); stage A-h1(u)
#pragma unroll
    for (int j = 0; j < 2; ++j) {
      a[j][0] = *(const f16x8*)(pA0 + 32768 + (2 + j) * 2048);
      a[j][1] = *(const f16x8*)(pA1 + 32768 + (2 + j) * 2048);
    }
    if (su) STG_A(0, 1, u);
    LGKM0(); BARRIER(); SCHED0();
    QUAD(2, b, a);

    // ---- ph7: A-q2(t1); stage B-h0(v)->Bbuf1 (freed at ph5 barrier)
#pragma unroll
    for (int j = 0; j < 2; ++j) {
      a[j][0] = *(const f16x8*)(pA0 + 32768 + (4 + j) * 2048);
      a[j][1] = *(const f16x8*)(pA1 + 32768 + (4 + j) * 2048);
    }
    if (sv) STG_B(32768, 0, v);
    LGKM0(); BARRIER(); SCHED0();
    QUAD(4, b, a);

    // ---- ph8: A-q3(t1); stage B-h1(v); vmcnt(4) => thru A(u) landed
#pragma unroll
    for (int j = 0; j < 2; ++j) {
      a[j][0] = *(const f16x8*)(pA0 + 32768 + (6 + j) * 2048);
      a[j][1] = *(const f16x8*)(pA1 + 32768 + (6 + j) * 2048);
    }
    if (sv) STG_B(32768, 1, v);
    LGKM0();
    if (sv) { VMW4(); } else { VMW0(); }
    BARRIER(); SCHED0();
    QUAD(6, b, a);
  }

#pragma unroll
  for (int nf = 0; nf < 4; ++nf) {
    const int col = bn0 + wc0 + nf * 16 + fr;
    const float bv = bias[col];
#pragma unroll
    for (int m = 0; m < 8; ++m) {
      const int row0 = bm0 + wr0 + m * 16 + fq * 4;
#pragma unroll
      for (int r = 0; r < 4; ++r) {
        float v = fmaxf(acc[m][nf][r] + bv, 0.f);
        C[(size_t)(row0 + r) * ldc + col] = (f16)v;
      }
    }
  }
}

// ---------------------------------------------------------------------------
// Heads: mean = h12@Wm^T + bm ; log_std = clip(h22@Wls^T + bls, -20, 2). fp32 out.
// ---------------------------------------------------------------------------
__global__ __launch_bounds__(256) void head_kernel(
    const f16* __restrict__ H1, const f16* __restrict__ H2,
    const f16* __restrict__ Wm, const float* __restrict__ bm,
    const f16* __restrict__ Wls, const float* __restrict__ bls,
    float* __restrict__ OUT, int M, int K)
{
  const int tid = threadIdx.x, wid = tid >> 6, lane = tid & 63;
  const int m0 = blockIdx.x * 64 + wid * 16;
  const int kb = (lane >> 4) * 8, fr = lane & 15, fq = lane >> 4;

  f32x4 a1[2] = {}, a2[2] = {};
  for (int k0 = 0; k0 < K; k0 += 32) {
    f16x8 f1 = *(const f16x8*)&H1[(size_t)(m0 + fr) * K + k0 + kb];
    f16x8 f2 = *(const f16x8*)&H2[(size_t)(m0 + fr) * K + k0 + kb];
#pragma unroll
    for (int n = 0; n < 2; ++n) {
      f16x8 wm = *(const f16x8*)&Wm[(size_t)(n * 16 + fr) * K + k0 + kb];
      f16x8 wl = *(const f16x8*)&Wls[(size_t)(n * 16 + fr) * K + k0 + kb];
      a1[n] = MFMA16(f1, wm, a1[n]);
      a2[n] = MFMA16(f2, wl, a2[n]);
    }
  }

#pragma unroll
  for (int n = 0; n < 2; ++n) {
    const int col = n * 16 + fr;
    const float bvm = bm[col];
    const float bvl = bls[col];
#pragma unroll
    for (int r = 0; r < 4; ++r) {
      const int row = m0 + fq * 4 + r;
      OUT[(size_t)row * 32 + col] = a1[n][r] + bvm;
      float lv = a2[n][r] + bvl;
      OUT[(size_t)M * 32 + (size_t)row * 32 + col] = fminf(fmaxf(lv, -20.f), 2.f);
    }
  }
}

// ---------------------------------------------------------------------------
extern "C" void kernel_launch(void* const* d_in, const int* in_sizes, int n_in,
                              void* d_out, int out_size, void* d_ws, size_t ws_size,
                              hipStream_t stream) {
  const float* state = (const float*)d_in[0];
  const float* W_lif = (const float*)d_in[1];
  const float* b_lif = (const float*)d_in[2];
  const float* W11   = (const float*)d_in[3];
  const float* b11   = (const float*)d_in[4];
  const float* W12   = (const float*)d_in[5];
  const float* b12   = (const float*)d_in[6];
  const float* W21   = (const float*)d_in[7];
  const float* b21   = (const float*)d_in[8];
  const float* W22   = (const float*)d_in[9];
  const float* b22   = (const float*)d_in[10];
  const float* Wm    = (const float*)d_in[11];
  const float* bm    = (const float*)d_in[12];
  const float* Wls   = (const float*)d_in[13];
  const float* bls   = (const float*)d_in[14];
  float* out = (float*)d_out;

  const int B = 4096, H = 2048;
  char* ws = (char*)d_ws;
  // layout (bytes), peak 84,148,224:
  f16* x    = (f16*)(ws);
  f16* s16  = (f16*)(ws + 16777216);
  f16* h1   = (f16*)(ws + 16777216);
  f16* h2   = (f16*)(ws + 33554432);
  f16* wl16 = (f16*)(ws + 37748736);
  f16* w4   = (f16*)(ws + 50331648);
  f16* w11h = (f16*)(ws + 50331648);
  f16* w21h = (f16*)(ws + 58720256);
  f16* h22  = (f16*)(ws + 50331648);
  f16* w12h = (f16*)(ws + 67108864);
  f16* w22h = (f16*)(ws + 75497472);
  f16* wmh  = (f16*)(ws + 83886080);
  f16* wlsh = (f16*)(ws + 84017152);
  f16* h12  = x;

  // 1) ALL converts in one dispatch
  cvtall_kernel<<<13888, 256, 0, stream>>>(
      state, W_lif, W11, W21, W12, W22, Wm, Wls,
      s16, wl16, w4, wmh, wlsh);

  // 2) fused fc-GEMM + LIF -> x
  lif256_kernel<<<256, 512, 0, stream>>>(s16, wl16, b_lif, x);

  // 3) trunk layer-1 (fused dual-output; h1/h2 overwrite dead s16/wl16)
  trunk256_kernel<<<256, 512, 0, stream>>>(x, x, H, w11h, w21h, b11, b21,
                                           h1, h2, H, 16, 8, H);
  // 4) trunk layer-2 -> h12 (over x), h22 (over dead w11h/w21h)
  trunk256_kernel<<<256, 512, 0, stream>>>(h1, h2, H, w12h, w22h, b12, b22,
                                           h12, h22, H, 16, 8, H);

  // 5) heads -> d_out = [mean | log_std] fp32
  head_kernel<<<B / 64, 256, 0, stream>>>(h12, h22, wmh, bm, wlsh, bls, out, B, H);
}